// Round 5
// baseline (155.058 us; speedup 1.0000x reference)
//
#include <hip/hip_runtime.h>

#define D 1536
#define BT 96          // square output tile
#define BK 64          // K-step
#define NT (D / BK)    // 24 K-steps
#define TT 64
#define TILE_E (BT * BK)       // 6144 elements per staged tile
#define BUF_E (4 * TILE_E)     // A_uc | A_lc | Bu | Bl = 24576 elements (48 KiB)

typedef unsigned short u16;
typedef short bf16x8 __attribute__((ext_vector_type(8)));
typedef short short2v __attribute__((ext_vector_type(2)));
typedef float f32x4 __attribute__((ext_vector_type(4)));

static __device__ __forceinline__ float bf2f(u16 s) {
    unsigned u = ((unsigned)s) << 16;
    float f; __builtin_memcpy(&f, &u, 4); return f;
}
static __device__ __forceinline__ u16 f2bf(float f) {
    unsigned u; __builtin_memcpy(&u, &f, 4);
    unsigned r = (u + 0x7FFFu + ((u >> 16) & 1u)) >> 16;
    return (u16)r;
}

// split packed bf16 x8 into positive part and negative part (sign-mask trick)
static __device__ __forceinline__ void splitpn(bf16x8 a, bf16x8& p, bf16x8& n) {
    union U { bf16x8 v; short2v s[4]; unsigned u[4]; } x, up, un;
    x.v = a;
#pragma unroll
    for (int i = 0; i < 4; ++i) {
        short2v m = x.s[i] >> 15;          // 0xFFFF where sign set
        unsigned mu; __builtin_memcpy(&mu, &m, 4);
        unsigned ng = x.u[i] & mu;         // keep where negative
        un.u[i] = ng;
        up.u[i] = x.u[i] ^ ng;             // keep where non-negative
    }
    p = up.v; n = un.v;
}

#define GLDS(g, s) __builtin_amdgcn_global_load_lds( \
    (const __attribute__((address_space(1))) void*)(g), \
    (__attribute__((address_space(3))) void*)(s), 16, 0, 0)

#define MFMA16(a, b, c) __builtin_amdgcn_mfma_f32_16x16x32_bf16(a, b, c, 0, 0, 0)

// ---------------- prep: z=0..5 transpose+convert lcs/ucs[0..2]; z=6,7 convert layer-3 ----------------
__global__ __launch_bounds__(256) void prep_k(
    const float* __restrict__ lcs, const float* __restrict__ ucs,
    u16* __restrict__ lcsT, u16* __restrict__ ucsT,
    u16* __restrict__ Ga, u16* __restrict__ Gc)
{
    const int z = blockIdx.z;
    const int r0 = blockIdx.y * TT, c0 = blockIdx.x * TT;
    const int tid = threadIdx.x;

    if (z >= 6) {  // straight convert: ucs[3]->Ga (z=6), lcs[3]->Gc (z=7)
        const float* src = (z == 6 ? ucs : lcs) + (size_t)3 * D * D;
        u16* dst = (z == 6) ? Ga : Gc;
#pragma unroll
        for (int i = 0; i < 2; ++i) {
            int r = (tid >> 3) + i * 32, cc = (tid & 7) * 8;
            const float* p = src + (size_t)(r0 + r) * D + c0 + cc;
            f32x4 x0 = *(const f32x4*)p;
            f32x4 x1 = *(const f32x4*)(p + 4);
            bf16x8 y;
#pragma unroll
            for (int e = 0; e < 4; ++e) { y[e] = (short)f2bf(x0[e]); y[e + 4] = (short)f2bf(x1[e]); }
            *(bf16x8*)(dst + (size_t)(r0 + r) * D + c0 + cc) = y;
        }
        return;
    }

    __shared__ u16 t[TT][TT + 8];
    const int j = z >> 1, sel = z & 1;
    const float* src = (sel ? ucs : lcs) + (size_t)j * D * D;
    u16* dst = (sel ? ucsT : lcsT) + (size_t)j * D * D;
#pragma unroll
    for (int i = 0; i < 2; ++i) {
        int c = tid + i * 256; int r = c >> 3, v = c & 7;
        const float* p = src + (size_t)(r0 + r) * D + c0 + v * 8;
        f32x4 x0 = *(const f32x4*)p;
        f32x4 x1 = *(const f32x4*)(p + 4);
        bf16x8 y;
#pragma unroll
        for (int e = 0; e < 4; ++e) { y[e] = (short)f2bf(x0[e]); y[e + 4] = (short)f2bf(x1[e]); }
        *(bf16x8*)&t[r][v * 8] = y;
    }
    __syncthreads();
#pragma unroll
    for (int i = 0; i < 2; ++i) {
        int c = tid + i * 256; int rr = c >> 3, v = c & 7;
        bf16x8 x;
#pragma unroll
        for (int e = 0; e < 8; ++e) x[e] = (short)t[v * 8 + e][rr];
        *(bf16x8*)(dst + (size_t)(c0 + rr) * D + r0 + v * 8) = x;
    }
}

// ---------------- vec: lb0/ub0 rows + cb init (layer-3 bias + j=2 bias update), all f32 ----------------
__global__ __launch_bounds__(256) void vec_k(
    const float* __restrict__ lb, const float* __restrict__ ub,
    const float* __restrict__ lcs, const float* __restrict__ ucs,
    const float* __restrict__ lcb, const float* __restrict__ ucb,
    float* __restrict__ lb0, float* __restrict__ ub0,
    float* __restrict__ cb_uc, float* __restrict__ cb_lc)
{
    const int tt = blockIdx.x * 4 + (threadIdx.x >> 6);
    const int lane = threadIdx.x & 63;
    const int which = tt / D;           // 0:lb0 1:ub0 2:cb_uc 3:cb_lc
    const int row_n = tt - which * D;

    const float* row; const float* vp; const float* vn;
    if (which == 0)      { row = lcs + (size_t)row_n * D;               vp = lb;           vn = ub; }
    else if (which == 1) { row = ucs + (size_t)row_n * D;               vp = ub;           vn = lb; }
    else if (which == 2) { row = ucs + (size_t)(3 * (size_t)D * D) + (size_t)row_n * D; vp = ucb + 2 * D; vn = lcb + 2 * D; }
    else                 { row = lcs + (size_t)(3 * (size_t)D * D) + (size_t)row_n * D; vp = lcb + 2 * D; vn = ucb + 2 * D; }

    float s = 0.f;
    for (int c2 = 0; c2 < D / 256; ++c2) {
        int base = (c2 * 64 + lane) * 4;
        f32x4 g = *(const f32x4*)(row + base);
        f32x4 p = *(const f32x4*)(vp + base);
        f32x4 m = *(const f32x4*)(vn + base);
#pragma unroll
        for (int e = 0; e < 4; ++e) s += g[e] * (g[e] > 0.f ? p[e] : m[e]);
    }
#pragma unroll
    for (int o = 32; o; o >>= 1) s += __shfl_down(s, o);
    if (lane == 0) {
        if (which == 0)      lb0[row_n] = s + lcb[row_n];
        else if (which == 1) ub0[row_n] = s + ucb[row_n];
        else if (which == 2) cb_uc[row_n] = s + ucb[3 * D + row_n];
        else                 cb_lc[row_n] = s + lcb[3 * D + row_n];
    }
}

// ---------------- fused-chain GEMM step ----------------
// One block computes BOTH chains' 96x96 tile:
//   outU = pos(Guc)@ucsT' + neg(Guc)@lcsT'   (B frags shared across chains)
//   outL = pos(Glc)@lcsT' + neg(Glc)@ucsT'
// 3-buffer LDS, 2-deep prefetch with counted vmcnt (T4); XOR-swizzle slot^(row&7)
// via pre-swizzled global source (rule #21). Fused bias-recurrence epilogue.

static __device__ __forceinline__ void stage_tile(
    const u16* __restrict__ Au, const u16* __restrict__ Al,
    const u16* __restrict__ Bu, const u16* __restrict__ Bl,
    int r0, int c0, int kt, u16* __restrict__ sbuf, int tid, int wid)
{
#pragma unroll
    for (int i = 0; i < 12; ++i) {
        const int idx = (i % 3) * 256 + tid;
        const int row = idx >> 3;                 // 0..95
        const int kcg = (tid & 7) ^ (row & 7);    // pre-swizzled global k-slot
        const u16* base; int ro;
        if (i < 3)      { base = Au; ro = r0; }
        else if (i < 6) { base = Al; ro = r0; }
        else if (i < 9) { base = Bu; ro = c0; }
        else            { base = Bl; ro = c0; }
        GLDS(base + (size_t)(ro + row) * D + kt + kcg * 8,
             (char*)sbuf + (i * 256 + wid * 64) * 16);
    }
}

static __device__ __forceinline__ void compute_tile(
    const u16* __restrict__ sbuf, f32x4 (&accU)[3][3], f32x4 (&accL)[3][3],
    int mb, int nb, int lrow, int lk)
{
#pragma unroll
    for (int ks = 0; ks < 2; ++ks) {
        const int slot = ks * 4 + lk;
        bf16x8 pu[3], nu[3], pl[3], nl[3];
#pragma unroll
        for (int mi = 0; mi < 3; ++mi) {
            int row = mb + mi * 16 + lrow;
            int x = slot ^ (row & 7);
            bf16x8 au = *(const bf16x8*)(sbuf + row * BK + x * 8);
            bf16x8 al = *(const bf16x8*)(sbuf + TILE_E + row * BK + x * 8);
            splitpn(au, pu[mi], nu[mi]);
            splitpn(al, pl[mi], nl[mi]);
        }
#pragma unroll
        for (int ni = 0; ni < 3; ++ni) {
            int row = nb + ni * 16 + lrow;
            int x = slot ^ (row & 7);
            bf16x8 bu = *(const bf16x8*)(sbuf + 2 * TILE_E + row * BK + x * 8);
            bf16x8 bl = *(const bf16x8*)(sbuf + 3 * TILE_E + row * BK + x * 8);
#pragma unroll
            for (int mi = 0; mi < 3; ++mi) {
                accU[mi][ni] = MFMA16(pu[mi], bu, accU[mi][ni]);
                accU[mi][ni] = MFMA16(nu[mi], bl, accU[mi][ni]);
                accL[mi][ni] = MFMA16(pl[mi], bl, accL[mi][ni]);
                accL[mi][ni] = MFMA16(nl[mi], bu, accL[mi][ni]);
            }
        }
    }
}

__global__ __launch_bounds__(256, 1) void gemm_step(
    const u16* __restrict__ Guc, const u16* __restrict__ Glc,
    const u16* __restrict__ lcsTj, const u16* __restrict__ ucsTj,
    u16* __restrict__ outU, u16* __restrict__ outL,
    const float* __restrict__ ucbN, const float* __restrict__ lcbN,
    float* __restrict__ cb_uc, float* __restrict__ cb_lc)
{
    __shared__ u16 smem[3 * BUF_E];          // 3 x 48 KiB
    const int r0 = blockIdx.y * BT, c0 = blockIdx.x * BT;
    const int tid = threadIdx.x, lane = tid & 63, wid = tid >> 6;
    const int mb = (wid >> 1) * 48, nb = (wid & 1) * 48;
    const int lrow = lane & 15, lk = lane >> 4;

    f32x4 accU[3][3] = {}, accL[3][3] = {};

    // prologue: stage tiles 0,1 (24 outstanding per wave)
    stage_tile(Guc, Glc, ucsTj, lcsTj, r0, c0, 0, smem, tid, wid);
    stage_tile(Guc, Glc, ucsTj, lcsTj, r0, c0, BK, smem + BUF_E, tid, wid);

#pragma unroll 1
    for (int t = 0; t < NT; ++t) {
        if (t + 2 < NT) {
            stage_tile(Guc, Glc, ucsTj, lcsTj, r0, c0, (t + 2) * BK,
                       smem + ((t + 2) % 3) * BUF_E, tid, wid);
            asm volatile("s_waitcnt vmcnt(24)" ::: "memory");  // t's 12 loads done
        } else if (t + 2 == NT) {
            asm volatile("s_waitcnt vmcnt(12)" ::: "memory");
        } else {
            asm volatile("s_waitcnt vmcnt(0)" ::: "memory");
        }
        __builtin_amdgcn_s_barrier();        // all waves' t-loads visible
        compute_tile(smem + (t % 3) * BUF_E, accU, accL, mb, nb, lrow, lk);
        asm volatile("" ::: "memory");
        __builtin_amdgcn_s_barrier();        // reads done before buf reuse
    }

    // fused bias recurrence for next backsub step (from f32 accumulators)
    if (ucbN) {
        float ubv[3], lbv[3];
#pragma unroll
        for (int ni = 0; ni < 3; ++ni) {
            int c = c0 + nb + ni * 16 + lrow;
            ubv[ni] = ucbN[c]; lbv[ni] = lcbN[c];
        }
#pragma unroll
        for (int mi = 0; mi < 3; ++mi)
#pragma unroll
            for (int q = 0; q < 4; ++q) {
                float sU = 0.f, sL = 0.f;
#pragma unroll
                for (int ni = 0; ni < 3; ++ni) {
                    float gU = accU[mi][ni][q];
                    float gL = accL[mi][ni][q];
                    sU += gU * (gU > 0.f ? ubv[ni] : lbv[ni]);
                    sL += gL * (gL > 0.f ? lbv[ni] : ubv[ni]);
                }
                sU += __shfl_xor(sU, 1); sU += __shfl_xor(sU, 2);
                sU += __shfl_xor(sU, 4); sU += __shfl_xor(sU, 8);
                sL += __shfl_xor(sL, 1); sL += __shfl_xor(sL, 2);
                sL += __shfl_xor(sL, 4); sL += __shfl_xor(sL, 8);
                if (lrow == 0) {
                    int r = r0 + mb + mi * 16 + lk * 4 + q;
                    atomicAdd(&cb_uc[r], sU);
                    atomicAdd(&cb_lc[r], sL);
                }
            }
    }

#pragma unroll
    for (int mi = 0; mi < 3; ++mi)
#pragma unroll
        for (int ni = 0; ni < 3; ++ni) {
            int c = c0 + nb + ni * 16 + lrow;
            int rbase = r0 + mb + mi * 16 + lk * 4;
#pragma unroll
            for (int q = 0; q < 4; ++q) {
                outU[(size_t)(rbase + q) * D + c] = f2bf(accU[mi][ni][q]);
                outL[(size_t)(rbase + q) * D + c] = f2bf(accL[mi][ni][q]);
            }
        }
}

// ---------------- final apply to layer-0 bounds, write f32 output ----------------
__global__ __launch_bounds__(256) void final_k(
    const u16* __restrict__ Guc, const u16* __restrict__ Glc,
    const float* __restrict__ cb_uc, const float* __restrict__ cb_lc,
    const float* __restrict__ lb0, const float* __restrict__ ub0,
    float* __restrict__ out)
{
    const int gw = blockIdx.x * 4 + (threadIdx.x >> 6);
    const int lane = threadIdx.x & 63;
    const int which = gw >= D;          // 0: cur_lb (G_lc), 1: cur_ub (G_uc)
    const int n = which ? gw - D : gw;
    const u16* row = (which ? Guc : Glc) + (size_t)n * D;
    const float* vp = which ? ub0 : lb0;
    const float* vn = which ? lb0 : ub0;
    float s = 0.f;
    for (int c2 = 0; c2 < D / 512; ++c2) {
        int base = (c2 * 64 + lane) * 8;
        bf16x8 g8 = *(const bf16x8*)(row + base);
        f32x4 p0 = *(const f32x4*)(vp + base);
        f32x4 p1 = *(const f32x4*)(vp + base + 4);
        f32x4 n0 = *(const f32x4*)(vn + base);
        f32x4 n1 = *(const f32x4*)(vn + base + 4);
#pragma unroll
        for (int e = 0; e < 8; ++e) {
            float g = bf2f((u16)g8[e]);
            float pv = e < 4 ? p0[e] : p1[e - 4];
            float nv = e < 4 ? n0[e] : n1[e - 4];
            s += g * (g > 0.f ? pv : nv);
        }
    }
#pragma unroll
    for (int o = 32; o; o >>= 1) s += __shfl_down(s, o);
    if (lane == 0) {
        float b = (which ? cb_uc : cb_lc)[n];
        out[which * D + n] = s + b;
    }
}

extern "C" void kernel_launch(void* const* d_in, const int* in_sizes, int n_in,
                              void* d_out, int out_size, void* d_ws, size_t ws_size,
                              hipStream_t stream) {
    const float* lb  = (const float*)d_in[0];
    const float* ub  = (const float*)d_in[1];
    const float* lcs = (const float*)d_in[2];
    const float* ucs = (const float*)d_in[3];
    const float* lcb = (const float*)d_in[4];
    const float* ucb = (const float*)d_in[5];
    float* out = (float*)d_out;

    const size_t DD = (size_t)D * D;
    u16* ws   = (u16*)d_ws;
    u16* lcsT = ws;                 // 3*D*D bf16, [N][K] layout
    u16* ucsT = lcsT + 3 * DD;      // 3*D*D bf16
    u16* Ga = ucsT + 3 * DD;        // G ping-pong buffers (bf16)
    u16* Gb = Ga + DD;
    u16* Gc = Gb + DD;
    u16* Gd = Gc + DD;
    float* fbuf  = (float*)(Gd + DD);
    float* lb0   = fbuf;
    float* ub0   = fbuf + D;
    float* cb_uc = fbuf + 2 * D;
    float* cb_lc = fbuf + 3 * D;

    // transposes + layer-3 converts in one launch
    prep_k<<<dim3(D / TT, D / TT, 8), 256, 0, stream>>>(lcs, ucs, lcsT, ucsT, Ga, Gc);
    // lb0/ub0 + cb init (layer-3 bias + j=2 bias update), pure f32
    vec_k<<<dim3(4 * D / 4), 256, 0, stream>>>(lb, ub, lcs, ucs, lcb, ucb, lb0, ub0, cb_uc, cb_lc);

    u16* curU = Ga; u16* curL = Gc;
    u16* altU = Gb; u16* altL = Gd;
    for (int j = 2; j >= 0; --j) {
        const float* ucbN = (j > 0) ? (ucb + (size_t)(j - 1) * D) : nullptr;
        const float* lcbN = (j > 0) ? (lcb + (size_t)(j - 1) * D) : nullptr;
        gemm_step<<<dim3(D / BT, D / BT), 256, 0, stream>>>(
            curU, curL, lcsT + (size_t)j * DD, ucsT + (size_t)j * DD, altU, altL,
            ucbN, lcbN, cb_uc, cb_lc);
        u16* t;
        t = curU; curU = altU; altU = t;
        t = curL; curL = altL; altL = t;
    }
    final_k<<<dim3(2 * D / 4), 256, 0, stream>>>(curU, curL, cb_uc, cb_lc, lb0, ub0, out);
}

// Round 6
// 128.185 us; speedup vs baseline: 1.2096x; 1.2096x over previous
//
#include <hip/hip_runtime.h>

#define D 1536
#define BT 96          // square output tile
#define BK 64          // K-step
#define NT (D / BK)    // 24 K-steps
#define TT 64
#define TILE_E (BT * BK)       // 6144 elements per staged tile (12 KiB)
#define BUF_E (3 * TILE_E)     // A | Bs | Bd per buffer (36 KiB)

typedef unsigned short u16;
typedef short bf16x8 __attribute__((ext_vector_type(8)));
typedef float f32x4 __attribute__((ext_vector_type(4)));

static __device__ __forceinline__ u16 f2bf(float f) {
    unsigned u; __builtin_memcpy(&u, &f, 4);
    unsigned r = (u + 0x7FFFu + ((u >> 16) & 1u)) >> 16;
    return (u16)r;
}
static __device__ __forceinline__ float bf2f(u16 s) {
    unsigned u = ((unsigned)s) << 16;
    float f; __builtin_memcpy(&f, &u, 4); return f;
}

#define GLDS(g, s) __builtin_amdgcn_global_load_lds( \
    (const __attribute__((address_space(1))) void*)(g), \
    (__attribute__((address_space(3))) void*)(s), 16, 0, 0)

#define MFMA16(a, b, c) __builtin_amdgcn_mfma_f32_16x16x32_bf16(a, b, c, 0, 0, 0)

// ---------------- prep ----------------
// z=0..2: layer z: BsT[z] = bf16((ucs[z]+lcs[z])/2)^T, BdT[z] = bf16((ucs[z]-lcs[z])/2)^T
// z=3:    convert ucs[3]->Ga, lcs[3]->Gc (bf16, untransposed)
__global__ __launch_bounds__(256) void prep_k(
    const float* __restrict__ lcs, const float* __restrict__ ucs,
    u16* __restrict__ BsT, u16* __restrict__ BdT,
    u16* __restrict__ Ga, u16* __restrict__ Gc)
{
    const int z = blockIdx.z;
    const int r0 = blockIdx.y * TT, c0 = blockIdx.x * TT;
    const int tid = threadIdx.x;

    if (z == 3) {
#pragma unroll
        for (int m = 0; m < 2; ++m) {
            const float* src = (m ? lcs : ucs) + (size_t)3 * D * D;
            u16* dst = m ? Gc : Ga;
#pragma unroll
            for (int i = 0; i < 2; ++i) {
                int r = (tid >> 3) + i * 32, cc = (tid & 7) * 8;
                const float* p = src + (size_t)(r0 + r) * D + c0 + cc;
                f32x4 x0 = *(const f32x4*)p;
                f32x4 x1 = *(const f32x4*)(p + 4);
                bf16x8 y;
#pragma unroll
                for (int e = 0; e < 4; ++e) { y[e] = (short)f2bf(x0[e]); y[e + 4] = (short)f2bf(x1[e]); }
                *(bf16x8*)(dst + (size_t)(r0 + r) * D + c0 + cc) = y;
            }
        }
        return;
    }

    __shared__ u16 ts[TT][TT + 8];
    __shared__ u16 td[TT][TT + 8];
    const float* srcl = lcs + (size_t)z * D * D;
    const float* srcu = ucs + (size_t)z * D * D;
#pragma unroll
    for (int i = 0; i < 2; ++i) {
        int c = tid + i * 256; int r = c >> 3, v = c & 7;
        size_t off = (size_t)(r0 + r) * D + c0 + v * 8;
        f32x4 l0 = *(const f32x4*)(srcl + off);
        f32x4 l1 = *(const f32x4*)(srcl + off + 4);
        f32x4 u0 = *(const f32x4*)(srcu + off);
        f32x4 u1 = *(const f32x4*)(srcu + off + 4);
        bf16x8 ys, yd;
#pragma unroll
        for (int e = 0; e < 4; ++e) {
            ys[e]     = (short)f2bf((u0[e] + l0[e]) * 0.5f);
            yd[e]     = (short)f2bf((u0[e] - l0[e]) * 0.5f);
            ys[e + 4] = (short)f2bf((u1[e] + l1[e]) * 0.5f);
            yd[e + 4] = (short)f2bf((u1[e] - l1[e]) * 0.5f);
        }
        *(bf16x8*)&ts[r][v * 8] = ys;
        *(bf16x8*)&td[r][v * 8] = yd;
    }
    __syncthreads();
#pragma unroll
    for (int i = 0; i < 2; ++i) {
        int c = tid + i * 256; int rr = c >> 3, v = c & 7;
        bf16x8 xs, xd;
#pragma unroll
        for (int e = 0; e < 8; ++e) { xs[e] = (short)ts[v * 8 + e][rr]; xd[e] = (short)td[v * 8 + e][rr]; }
        size_t off = (size_t)z * D * D + (size_t)(c0 + rr) * D + r0 + v * 8;
        *(bf16x8*)(BsT + off) = xs;
        *(bf16x8*)(BdT + off) = xd;
    }
}

// ---------------- vec: lb0/ub0 rows + cb init (layer-3 bias + j=2 bias update), all f32 ----------------
__global__ __launch_bounds__(256) void vec_k(
    const float* __restrict__ lb, const float* __restrict__ ub,
    const float* __restrict__ lcs, const float* __restrict__ ucs,
    const float* __restrict__ lcb, const float* __restrict__ ucb,
    float* __restrict__ lb0, float* __restrict__ ub0,
    float* __restrict__ cb_uc, float* __restrict__ cb_lc)
{
    const int tt = blockIdx.x * 4 + (threadIdx.x >> 6);
    const int lane = threadIdx.x & 63;
    const int which = tt / D;           // 0:lb0 1:ub0 2:cb_uc 3:cb_lc
    const int row_n = tt - which * D;

    const float* row; const float* vp; const float* vn;
    if (which == 0)      { row = lcs + (size_t)row_n * D;               vp = lb;           vn = ub; }
    else if (which == 1) { row = ucs + (size_t)row_n * D;               vp = ub;           vn = lb; }
    else if (which == 2) { row = ucs + (size_t)(3 * (size_t)D * D) + (size_t)row_n * D; vp = ucb + 2 * D; vn = lcb + 2 * D; }
    else                 { row = lcs + (size_t)(3 * (size_t)D * D) + (size_t)row_n * D; vp = lcb + 2 * D; vn = ucb + 2 * D; }

    float s = 0.f;
    for (int c2 = 0; c2 < D / 256; ++c2) {
        int base = (c2 * 64 + lane) * 4;
        f32x4 g = *(const f32x4*)(row + base);
        f32x4 p = *(const f32x4*)(vp + base);
        f32x4 m = *(const f32x4*)(vn + base);
#pragma unroll
        for (int e = 0; e < 4; ++e) s += g[e] * (g[e] > 0.f ? p[e] : m[e]);
    }
#pragma unroll
    for (int o = 32; o; o >>= 1) s += __shfl_down(s, o);
    if (lane == 0) {
        if (which == 0)      lb0[row_n] = s + lcb[row_n];
        else if (which == 1) ub0[row_n] = s + ucb[row_n];
        else if (which == 2) cb_uc[row_n] = s + ucb[3 * D + row_n];
        else                 cb_lc[row_n] = s + lcb[3 * D + row_n];
    }
}

// ---------------- GEMM step: out = A@Bs + sgn(|A|)@Bd ----------------
// chain 0 (uc): out = Guc@Bs + |Guc|@Bd ; chain 1 (lc): out = Glc@Bs - |Glc|@Bd.
// 96x96 tile, 4 waves (2x2), per-wave 48x48. Double-buffered LDS with counted
// vmcnt (2-deep prefetch), one stage per K-step. XOR-swizzle slot^(row&7) via
// pre-swizzled global source (rule #21). Fused bias-recurrence epilogue.

static __device__ __forceinline__ void stage_tile(
    const u16* __restrict__ A, const u16* __restrict__ Bs, const u16* __restrict__ Bd,
    int r0, int c0, int kt, u16* __restrict__ sbuf, int tid, int wid)
{
#pragma unroll
    for (int i = 0; i < 9; ++i) {
        const int idx = (i % 3) * 256 + tid;
        const int row = idx >> 3;                 // 0..95
        const int kcg = (tid & 7) ^ (row & 7);    // pre-swizzled global k-slot
        const u16* base = (i < 3) ? (A + (size_t)(r0 + row) * D)
                        : ((i < 6) ? (Bs + (size_t)(c0 + row) * D)
                                   : (Bd + (size_t)(c0 + row) * D));
        GLDS(base + kt + kcg * 8, (char*)sbuf + (i * 256 + wid * 64) * 16);
    }
}

static __device__ __forceinline__ void compute_tile(
    const u16* __restrict__ sbuf, f32x4 (&acc)[3][3], unsigned sgn,
    int mb, int nb, int lrow, int lk)
{
#pragma unroll
    for (int ks = 0; ks < 2; ++ks) {
        const int slot = ks * 4 + lk;
        bf16x8 a[3], x[3];
#pragma unroll
        for (int mi = 0; mi < 3; ++mi) {
            int row = mb + mi * 16 + lrow;
            int xx = slot ^ (row & 7);
            a[mi] = *(const bf16x8*)(sbuf + row * BK + xx * 8);
            union { bf16x8 v; unsigned u[4]; } t, o;
            t.v = a[mi];
#pragma unroll
            for (int q = 0; q < 4; ++q) o.u[q] = (t.u[q] & 0x7FFF7FFFu) ^ sgn;
            x[mi] = o.v;
        }
#pragma unroll
        for (int ni = 0; ni < 3; ++ni) {
            int row = nb + ni * 16 + lrow;
            int xx = slot ^ (row & 7);
            bf16x8 bs = *(const bf16x8*)(sbuf + TILE_E + row * BK + xx * 8);
            bf16x8 bd = *(const bf16x8*)(sbuf + 2 * TILE_E + row * BK + xx * 8);
#pragma unroll
            for (int mi = 0; mi < 3; ++mi) {
                acc[mi][ni] = MFMA16(a[mi], bs, acc[mi][ni]);
                acc[mi][ni] = MFMA16(x[mi], bd, acc[mi][ni]);
            }
        }
    }
}

__global__ __launch_bounds__(256, 2) void gemm_step(
    const u16* __restrict__ Guc, const u16* __restrict__ Glc,
    const u16* __restrict__ Bs, const u16* __restrict__ Bd,
    u16* __restrict__ outU, u16* __restrict__ outL,
    const float* __restrict__ ucbN, const float* __restrict__ lcbN,
    float* __restrict__ cb_uc, float* __restrict__ cb_lc)
{
    __shared__ u16 smem[2 * BUF_E];          // 2 x 36 KiB
    const int chain = blockIdx.z;
    const u16* A = chain ? Glc : Guc;
    u16* out = chain ? outL : outU;
    const unsigned sgn = chain ? 0x80008000u : 0u;   // -|A| for lc chain
    const int r0 = blockIdx.y * BT, c0 = blockIdx.x * BT;
    const int tid = threadIdx.x, lane = tid & 63, wid = tid >> 6;
    const int mb = (wid >> 1) * 48, nb = (wid & 1) * 48;
    const int lrow = lane & 15, lk = lane >> 4;

    f32x4 acc[3][3] = {};

    // prologue: stage tiles 0 and 1 (9+9 outstanding per wave)
    stage_tile(A, Bs, Bd, r0, c0, 0, smem, tid, wid);
    stage_tile(A, Bs, Bd, r0, c0, BK, smem + BUF_E, tid, wid);

#pragma unroll 1
    for (int t = 0; t < NT; ++t) {
        if (t < NT - 1) { asm volatile("s_waitcnt vmcnt(9)" ::: "memory"); }
        else            { asm volatile("s_waitcnt vmcnt(0)" ::: "memory"); }
        __builtin_amdgcn_sched_barrier(0);
        __builtin_amdgcn_s_barrier();        // tile t visible to all waves
        compute_tile(smem + (t & 1) * BUF_E, acc, sgn, mb, nb, lrow, lk);
        __builtin_amdgcn_s_barrier();        // all waves done reading buf[t&1]
        if (t + 2 < NT)
            stage_tile(A, Bs, Bd, r0, c0, (t + 2) * BK, smem + (t & 1) * BUF_E, tid, wid);
    }

    // fused bias recurrence for next backsub step (from f32 accumulators)
    if (ucbN) {
        const float* pb_ = chain ? lcbN : ucbN;
        const float* nb_ = chain ? ucbN : lcbN;
        float* cb = chain ? cb_lc : cb_uc;
        float pbv[3], nbv[3];
#pragma unroll
        for (int ni = 0; ni < 3; ++ni) {
            int c = c0 + nb + ni * 16 + lrow;
            pbv[ni] = pb_[c]; nbv[ni] = nb_[c];
        }
#pragma unroll
        for (int mi = 0; mi < 3; ++mi)
#pragma unroll
            for (int q = 0; q < 4; ++q) {
                float s = 0.f;
#pragma unroll
                for (int ni = 0; ni < 3; ++ni) {
                    float g = acc[mi][ni][q];
                    s += g * (g > 0.f ? pbv[ni] : nbv[ni]);
                }
                s += __shfl_xor(s, 1); s += __shfl_xor(s, 2);
                s += __shfl_xor(s, 4); s += __shfl_xor(s, 8);
                if (lrow == 0)
                    atomicAdd(&cb[r0 + mb + mi * 16 + lk * 4 + q], s);
            }
    }

#pragma unroll
    for (int mi = 0; mi < 3; ++mi)
#pragma unroll
        for (int ni = 0; ni < 3; ++ni) {
            int c = c0 + nb + ni * 16 + lrow;
            int rbase = r0 + mb + mi * 16 + lk * 4;
#pragma unroll
            for (int q = 0; q < 4; ++q)
                out[(size_t)(rbase + q) * D + c] = f2bf(acc[mi][ni][q]);
        }
}

// ---------------- final apply to layer-0 bounds, write f32 output ----------------
__global__ __launch_bounds__(256) void final_k(
    const u16* __restrict__ Guc, const u16* __restrict__ Glc,
    const float* __restrict__ cb_uc, const float* __restrict__ cb_lc,
    const float* __restrict__ lb0, const float* __restrict__ ub0,
    float* __restrict__ out)
{
    const int gw = blockIdx.x * 4 + (threadIdx.x >> 6);
    const int lane = threadIdx.x & 63;
    const int which = gw >= D;          // 0: cur_lb (G_lc), 1: cur_ub (G_uc)
    const int n = which ? gw - D : gw;
    const u16* row = (which ? Guc : Glc) + (size_t)n * D;
    const float* vp = which ? ub0 : lb0;
    const float* vn = which ? lb0 : ub0;
    float s = 0.f;
    for (int c2 = 0; c2 < D / 512; ++c2) {
        int base = (c2 * 64 + lane) * 8;
        bf16x8 g8 = *(const bf16x8*)(row + base);
        f32x4 p0 = *(const f32x4*)(vp + base);
        f32x4 p1 = *(const f32x4*)(vp + base + 4);
        f32x4 n0 = *(const f32x4*)(vn + base);
        f32x4 n1 = *(const f32x4*)(vn + base + 4);
#pragma unroll
        for (int e = 0; e < 8; ++e) {
            float g = bf2f((u16)g8[e]);
            float pv = e < 4 ? p0[e] : p1[e - 4];
            float nv = e < 4 ? n0[e] : n1[e - 4];
            s += g * (g > 0.f ? pv : nv);
        }
    }
#pragma unroll
    for (int o = 32; o; o >>= 1) s += __shfl_down(s, o);
    if (lane == 0) {
        float b = (which ? cb_uc : cb_lc)[n];
        out[which * D + n] = s + b;
    }
}

extern "C" void kernel_launch(void* const* d_in, const int* in_sizes, int n_in,
                              void* d_out, int out_size, void* d_ws, size_t ws_size,
                              hipStream_t stream) {
    const float* lb  = (const float*)d_in[0];
    const float* ub  = (const float*)d_in[1];
    const float* lcs = (const float*)d_in[2];
    const float* ucs = (const float*)d_in[3];
    const float* lcb = (const float*)d_in[4];
    const float* ucb = (const float*)d_in[5];
    float* out = (float*)d_out;

    const size_t DD = (size_t)D * D;
    u16* ws   = (u16*)d_ws;
    u16* BsT = ws;                  // 3*D*D bf16, [N][K] layout
    u16* BdT = BsT + 3 * DD;        // 3*D*D bf16
    u16* Ga = BdT + 3 * DD;         // G ping-pong buffers (bf16)
    u16* Gb = Ga + DD;
    u16* Gc = Gb + DD;
    u16* Gd = Gc + DD;
    float* fbuf  = (float*)(Gd + DD);
    float* lb0   = fbuf;
    float* ub0   = fbuf + D;
    float* cb_uc = fbuf + 2 * D;
    float* cb_lc = fbuf + 3 * D;

    // Bs/Bd transposes (exact f32 halves) + layer-3 converts in one launch
    prep_k<<<dim3(D / TT, D / TT, 4), 256, 0, stream>>>(lcs, ucs, BsT, BdT, Ga, Gc);
    // lb0/ub0 + cb init (layer-3 bias + j=2 bias update), pure f32
    vec_k<<<dim3(4 * D / 4), 256, 0, stream>>>(lb, ub, lcs, ucs, lcb, ucb, lb0, ub0, cb_uc, cb_lc);

    u16* curU = Ga; u16* curL = Gc;
    u16* altU = Gb; u16* altL = Gd;
    for (int j = 2; j >= 0; --j) {
        const float* ucbN = (j > 0) ? (ucb + (size_t)(j - 1) * D) : nullptr;
        const float* lcbN = (j > 0) ? (lcb + (size_t)(j - 1) * D) : nullptr;
        gemm_step<<<dim3(D / BT, D / BT, 2), 256, 0, stream>>>(
            curU, curL, BsT + (size_t)j * DD, BdT + (size_t)j * DD, altU, altL,
            ucbN, lcbN, cb_uc, cb_lc);
        u16* t;
        t = curU; curU = altU; altU = t;
        t = curL; curL = altL; altL = t;
    }
    final_k<<<dim3(2 * D / 4), 256, 0, stream>>>(curU, curL, cb_uc, cb_lc, lb0, ub0, out);
}